// Round 1
// baseline (1086.123 us; speedup 1.0000x reference)
//
#include <hip/hip_runtime.h>

#define TT 2048
#define BB 64
#define HH 256   // EMB == HID == 256

typedef _Float16 half2_t __attribute__((ext_vector_type(2)));
typedef _Float16 half8_t __attribute__((ext_vector_type(8)));
typedef float f32x4 __attribute__((ext_vector_type(4)));

static __device__ __forceinline__ float fdot2(half2_t a, half2_t b, float c) {
#if __has_builtin(__builtin_amdgcn_fdot2)
  return __builtin_amdgcn_fdot2(a, b, c, false);   // v_dot2_f32_f16, f32 accum
#else
  return c + (float)a[0] * (float)b[0] + (float)a[1] * (float)b[1];
#endif
}

// ---------------------------------------------------------------------------
// prep: transpose + fp16-convert W_ih and W_hh into [N][K] row-major.
// ---------------------------------------------------------------------------
__global__ void prep_kernel(const float* __restrict__ Wih, const float* __restrict__ Whh,
                            _Float16* __restrict__ WihT, _Float16* __restrict__ WhhT) {
  const int n = blockIdx.x;   // output column
  const int k = threadIdx.x;  // input row
  WihT[n * HH + k] = (_Float16)Wih[k * HH + n];
  WhhT[n * HH + k] = (_Float16)Whh[k * HH + n];
}

// ---------------------------------------------------------------------------
// Part A: U[t][b][n] = (emb[source[b][t]] @ W_ih)[n] + b_ih[n] + b_hh[n], fp16.
// (unchanged — verified correct; scan dominates runtime)
// ---------------------------------------------------------------------------
__global__ __launch_bounds__(256, 2) void embed_gemm_kernel(
    const int* __restrict__ source, const float* __restrict__ emb,
    const _Float16* __restrict__ WihT, const float* __restrict__ b_ih,
    const float* __restrict__ b_hh, _Float16* __restrict__ U) {
  const int t = blockIdx.x;
  const int nbase = blockIdx.y * 64;
  __shared__ __align__(16) _Float16 Bs[64][280];

  const int tid = threadIdx.x;
  for (int c = tid; c < 64 * 32; c += 256) {
    const int n = c >> 5;
    const int ko = (c & 31) * 8;
    *(half8_t*)&Bs[n][ko] = *(const half8_t*)(WihT + (size_t)(nbase + n) * HH + ko);
  }
  __syncthreads();

  const int lane = tid & 63;
  const int wave = tid >> 6;
  const int row16 = lane & 15;
  const int quad = lane >> 4;
  const int b = wave * 16 + row16;              // A-fragment row = batch
  const int src = source[b * TT + t];           // source is [B][T]
  const float* arow = emb + (size_t)src * HH + quad * 8;

  f32x4 acc[4];
#pragma unroll
  for (int ct = 0; ct < 4; ++ct) acc[ct] = (f32x4){0.f, 0.f, 0.f, 0.f};

#pragma unroll
  for (int kt = 0; kt < 8; ++kt) {
    const float4 x0 = *(const float4*)(arow + kt * 32);
    const float4 x1 = *(const float4*)(arow + kt * 32 + 4);
    half8_t af;
    af[0] = (_Float16)x0.x; af[1] = (_Float16)x0.y;
    af[2] = (_Float16)x0.z; af[3] = (_Float16)x0.w;
    af[4] = (_Float16)x1.x; af[5] = (_Float16)x1.y;
    af[6] = (_Float16)x1.z; af[7] = (_Float16)x1.w;
#pragma unroll
    for (int ct = 0; ct < 4; ++ct) {
      const half8_t bf = *(const half8_t*)&Bs[ct * 16 + row16][quad * 8 + kt * 32];
      acc[ct] = __builtin_amdgcn_mfma_f32_16x16x32_f16(af, bf, acc[ct], 0, 0, 0);
    }
  }

#pragma unroll
  for (int ct = 0; ct < 4; ++ct) {
    const int nn = nbase + ct * 16 + row16;     // C col = lane&15
    const float bias = b_ih[nn] + b_hh[nn];
#pragma unroll
    for (int r = 0; r < 4; ++r) {
      const int bb = wave * 16 + quad * 4 + r;  // C row = quad*4 + reg
      U[((size_t)t * BB + bb) * HH + nn] = (_Float16)(acc[ct][r] + bias);
    }
  }
}

// ---------------------------------------------------------------------------
// Part B: recurrence via VALU v_dot2_f32_f16 (R10).
//   R9 post-mortem: MfmaUtil 13.6% GPU-wide = ~54% on the 64 active CUs ->
//   the MFMA section is THE cost: 32 MFMA/wave at ~19.4 cy/SIMD ~ 620 cy of
//   the 942-cy step, with 15/16 of each MFMA wasted on the M-broadcast.
//   VALU dot2 does the same 65536 MACs/step in 256 cy/CU (2 MACs/lane/instr).
//
//   Decomposition: wave w owns k-slice [64w,64w+64). Thread (w,l) holds
//   W[k][n] for n in {l,64+l,128+l,192+l} over its slice (128 VGPRs, loaded
//   once; waves_per_eu(1,1) -> 512-reg budget) and produces 4 f32 partials
//   (4 independent fdot2 chains of 32 -> no dep stalls).
//   Partials cross waves through pbuf (pad 5 -> conflict-free; double-
//   buffered so max barrier skew 1 needs no 2nd barrier). Thread tid
//   finalizes n = tid, so next step's h-slice of wave w was written by its
//   OWN lanes -> h write->read needs no barrier (in-order DS pipe).
//   ONE barrier/step, raw "lgkmcnt(0); s_barrier" (no vmcnt drain -> the
//   8-step u prefetch stays in flight across barriers).
// ---------------------------------------------------------------------------
__global__ __launch_bounds__(256)
__attribute__((amdgpu_waves_per_eu(1, 1)))
void rnn_scan_kernel(
    const _Float16* __restrict__ U, const _Float16* __restrict__ WhhT,
    float* __restrict__ out) {
  const int b = blockIdx.x;
  const int tid = threadIdx.x;
  const int w = tid >> 6;    // wave = k-slice index
  const int l = tid & 63;

  __shared__ __align__(16) _Float16 hbuf[HH];   // single buffer: wave w's slice
                                                // is read ONLY by wave w (proof above)
  __shared__ float pbuf[2][HH][5];              // partials, padded, ping-pong

  // W fragments: thread (w,l) -> outputs {l,64+l,128+l,192+l}, k in [64w,64w+64).
  // One-time strided load (WhhT is 128 KB, L2-resident).
  half8_t wreg[4][8];
#pragma unroll
  for (int j = 0; j < 4; ++j) {
    const _Float16* wp = WhhT + (size_t)(64 * j + l) * HH + 64 * w;
#pragma unroll
    for (int r = 0; r < 8; ++r) wreg[j][r] = *(const half8_t*)(wp + 8 * r);
  }

  hbuf[tid] = (_Float16)0.f;  // h0 = 0

  // Thread tid finalizes output n = tid: u stream is per-thread contiguous.
  const _Float16* Up = U + b * HH + tid;  // step stride = BB*HH halfs
  _Float16 uc[8], un[8];
#pragma unroll
  for (int s = 0; s < 8; ++s) uc[s] = Up[(size_t)s * (BB * HH)];

  float hn = 0.f;
  __syncthreads();  // once, outside the loop (vmcnt drain here is harmless)

  for (int tc = 0; tc < TT; tc += 8) {
    // Issue next-chunk u-loads; raw barriers below never drain vmcnt, so
    // these stay in flight until the uc=un copy (8 steps of slack).
    const int tn = (tc + 8) & (TT - 1);
#pragma unroll
    for (int s = 0; s < 8; ++s) un[s] = Up[(size_t)(tn + s) * (BB * HH)];

#pragma unroll
    for (int s = 0; s < 8; ++s) {
      // ---- DOT: read own wave's h slice (64-lane broadcast, 8 x b128) ----
      const _Float16* hrow = hbuf + 64 * w;
      half8_t hv[8];
#pragma unroll
      for (int r = 0; r < 8; ++r) hv[r] = *(const half8_t*)(hrow + 8 * r);

      float a0 = 0.f, a1 = 0.f, a2 = 0.f, a3 = 0.f;
#pragma unroll
      for (int r = 0; r < 8; ++r) {
#pragma unroll
        for (int i = 0; i < 4; ++i) {
          const half2_t hh = {hv[r][2 * i], hv[r][2 * i + 1]};         // reg alias
          const half2_t w0 = {wreg[0][r][2 * i], wreg[0][r][2 * i + 1]};
          const half2_t w1 = {wreg[1][r][2 * i], wreg[1][r][2 * i + 1]};
          const half2_t w2 = {wreg[2][r][2 * i], wreg[2][r][2 * i + 1]};
          const half2_t w3 = {wreg[3][r][2 * i], wreg[3][r][2 * i + 1]};
          a0 = fdot2(hh, w0, a0);   // 4 independent chains, dep spacing 8 cy
          a1 = fdot2(hh, w1, a1);
          a2 = fdot2(hh, w2, a2);
          a3 = fdot2(hh, w3, a3);
        }
      }

      // ---- partials out: banks (5l + w) % 32 -> 2-way max (free) ----
      pbuf[s & 1][l][w]       = a0;
      pbuf[s & 1][64 + l][w]  = a1;
      pbuf[s & 1][128 + l][w] = a2;
      pbuf[s & 1][192 + l][w] = a3;

      // Raw barrier: wait own LDS ops only; u prefetch (vmcnt) unaffected.
      asm volatile("s_waitcnt lgkmcnt(0)\n\ts_barrier" ::: "memory");

      // ---- finalize n = tid: gather 4 partials, tanh, write h ----
      const float p0 = pbuf[s & 1][tid][0];
      const float p1 = pbuf[s & 1][tid][1];
      const float p2 = pbuf[s & 1][tid][2];
      const float p3 = pbuf[s & 1][tid][3];
      const float y = (p0 + p1) + (p2 + p3);
      const float a = (float)uc[s] + y;
      // tanh(a) = 1 - 2/(exp(2a)+1)
      const float e = __builtin_amdgcn_exp2f(a * 2.885390081777927f);  // 2*log2(e)
      hn = 1.f - 2.f * __builtin_amdgcn_rcpf(e + 1.f);
      hbuf[tid] = (_Float16)hn;   // own wave consumes this next step; no barrier
    }
#pragma unroll
    for (int s = 0; s < 8; ++s) uc[s] = un[s];
  }
  out[(size_t)b * HH + tid] = hn;
}

// ---------------------------------------------------------------------------
extern "C" void kernel_launch(void* const* d_in, const int* in_sizes, int n_in,
                              void* d_out, int out_size, void* d_ws, size_t ws_size,
                              hipStream_t stream) {
  const int*   source = (const int*)d_in[0];
  const float* emb    = (const float*)d_in[1];
  const float* Wih    = (const float*)d_in[2];
  const float* Whh    = (const float*)d_in[3];
  const float* bih    = (const float*)d_in[4];
  const float* bhh    = (const float*)d_in[5];
  float* out = (float*)d_out;

  char* ws = (char*)d_ws;
  _Float16* U    = (_Float16*)ws;                    // 2048*64*256*2 = 67,108,864 B
  _Float16* WihT = (_Float16*)(ws + 67108864);       // 131,072 B
  _Float16* WhhT = (_Float16*)(ws + 67239936);       // 131,072 B (total ~67.4 MB)

  prep_kernel<<<dim3(256), dim3(256), 0, stream>>>(Wih, Whh, WihT, WhhT);
  embed_gemm_kernel<<<dim3(TT, 4), dim3(256), 0, stream>>>(source, emb, WihT, bih, bhh, U);
  rnn_scan_kernel<<<dim3(BB), dim3(256), 0, stream>>>(U, WhhT, out);
}